// Round 14
// baseline (76.861 us; speedup 1.0000x reference)
//
#include <hip/hip_runtime.h>
#include <hip/hip_bf16.h>

typedef __attribute__((ext_vector_type(8))) short short8;
typedef __attribute__((ext_vector_type(4))) float floatx4;

#define BB 256
#define SS 512
#define VOCAB 50000
#define EMB_D 300
#define POS_MAX 512
#define POS_D 16
#define CNN_OUT 50
#define KW 5
#define NCLASS 10
#define C_IN 332            // EMB_D + 2*POS_D
#define KS2 10              // proj GEMM K-steps: 10 x 32 = 320 (K=300 zero-padded)
#define NB2 20              // 20 n-frags of 16 = 320 cols, layout col = k*64+o
#define NWF2 (KS2 * NB2 * 64 * 8)   // 102400 packed B elems
#define PSTR 320            // P/P1/P2 row stride in bf16 (640 B = 40 uint4)
#define ESTR 328            // proj LDS row stride (ushorts; 656B -> 4-bank row walk)
#define FSTR2 328           // conv LDS row stride (same reasoning)
#define MTOK 16             // tokens per proj wave-block
#define MROWS 64            // output positions per conv block
#define FROWS 68            // 64 + 2+2 halo
#define NB_PROJ 3125        // 50000/16
#define NB_POSP 640         // 2*512*320 / 512
#define NB_DIST BB

__device__ __forceinline__ unsigned pack2bf(float x, float y) {
    __hip_bfloat162 h = __float22bfloat162_rn(make_float2(x, y));   // v_cvt_pk_bf16_f32
    return *reinterpret_cast<unsigned*>(&h);
}

__device__ __forceinline__ unsigned short f2bf(float x) {
    unsigned u = __float_as_uint(x);
    u += 0x7FFF + ((u >> 16) & 1);      // RNE
    return (unsigned short)(u >> 16);
}

__device__ __forceinline__ float bflo(unsigned u) { return __uint_as_float(u << 16); }
__device__ __forceinline__ float bfhi(unsigned u) { return __uint_as_float(u & 0xFFFF0000u); }

// F = sa*a + sp*(b+c), elementwise on packed bf16 pairs, RNE repack
__device__ __forceinline__ unsigned comb(unsigned a, unsigned b, unsigned c,
                                         float sa, float sp) {
    float rlo = sa * bflo(a) + sp * (bflo(b) + bflo(c));
    float rhi = sa * bfhi(a) + sp * (bfhi(b) + bfhi(c));
    return pack2bf(rlo, rhi);
}

// ---------------- K0: Wf2 pack + ymax zero (tiny, precedes everything) ----------------
__global__ __launch_bounds__(256) void k_wf(const float* __restrict__ conv_w,
                                            unsigned short* __restrict__ Wf2,
                                            float* __restrict__ ymax) {
    int idx = blockIdx.x * 256 + threadIdx.x;
    if (idx < NWF2) {
        // ((ks*20+nb)*64+l)*8+j holds W[c=ks*32+(l>>4)*8+j][col=nb*16+(l&15)], col=k*64+o
        int j = idx & 7, l = (idx >> 3) & 63;
        int rest = idx >> 9;
        int nb = rest % 20, ks = rest / 20;
        int c = ks * 32 + ((l >> 4) << 3) + j;
        int col = nb * 16 + (l & 15);
        int k = col >> 6, o = col & 63;
        float v = 0.f;
        if (c < EMB_D && o < CNN_OUT)
            v = conv_w[o * (C_IN * KW) + c * KW + k];
        Wf2[idx] = f2bf(v);
    } else if (idx < NWF2 + BB * CNN_OUT) {
        ymax[idx - NWF2] = 0.f;   // relu >= 0: 0 is identity for the max
    }
}

// ---------------- K1: merged: barrier-free proj GEMM | pos-proj | distances ----------
// 64-thread (1-wave) blocks. Role by blockIdx range.
// proj (3125 blocks): 16 tokens/wave, wave-private LDS, NO __syncthreads in GEMM path:
// stage 19 float4 loads in flight -> cvt -> LDS; 4 col-groups of 80: 10 K-steps x 5 MFMA
// with 2-deep B ping-pong; transpose via private scratch; coalesced 16B stores.
__global__ __launch_bounds__(64) void k_merge(const float* __restrict__ E,
                                              const unsigned short* __restrict__ Wf2,
                                              unsigned short* __restrict__ P,
                                              int* __restrict__ rowz,
                                              const float* __restrict__ conv_w,
                                              const float* __restrict__ pos,
                                              unsigned short* __restrict__ P1,
                                              unsigned short* __restrict__ P2,
                                              const int* __restrict__ tokens,
                                              const int* __restrict__ e1p,
                                              const int* __restrict__ e2p,
                                              int* __restrict__ d1,
                                              int* __restrict__ d2) {
    __shared__ __align__(16) char smem[13248];
    int bid = blockIdx.x, lane = threadIdx.x;

    if (bid < NB_PROJ) {
        unsigned short* Elds = (unsigned short*)smem;              // 16*328*2 = 10496
        unsigned short* Sc   = (unsigned short*)(smem + 10496);    // 16*80*2  =  2560
        int* nzf             = (int*)(smem + 13056);               // 16*4
        int t0 = bid * MTOK;

        if (lane < MTOK) nzf[lane] = 0;
        // ---- stage: 1200 float4 chunks, 19 in flight per lane, no barrier ----
        #pragma unroll
        for (int j = 0; j < 19; ++j) {
            int idx = lane + j * 64;
            if (idx < MTOK * 75) {
                int row = idx / 75, c4 = idx - row * 75;
                float4 v = ((const float4*)(E + (size_t)(t0 + row) * EMB_D))[c4];
                if ((v.x != 0.f) | (v.y != 0.f) | (v.z != 0.f) | (v.w != 0.f)) nzf[row] = 1;
                *(uint2*)&Elds[row * ESTR + c4 * 4] =
                    make_uint2(pack2bf(v.x, v.y), pack2bf(v.z, v.w));
            }
        }
        #pragma unroll
        for (int j = 0; j < 2; ++j) {   // zero-pad cols 300..319 (16 rows x 5 uint2)
            int idx = lane + j * 64;
            if (idx < MTOK * 5) {
                int row = idx / 5, u = idx - row * 5;
                *(uint2*)&Elds[row * ESTR + 300 + u * 4] = make_uint2(0u, 0u);
            }
        }
        if (lane < MTOK) rowz[t0 + lane] = nzf[lane] ? 0 : 1;

        // ---- GEMM: 4 col-groups of 5 n-frags; 1 m-frag (16 tokens) ----
        int arow = lane & 15, ach = (lane >> 4) * 8;
        int drow = (lane >> 4) * 4, dcol = lane & 15;
        const short8* Bp = (const short8*)Wf2;
        #pragma unroll 1
        for (int g = 0; g < 4; ++g) {
            floatx4 acc[5];
            #pragma unroll
            for (int nb = 0; nb < 5; ++nb) acc[nb] = (floatx4)0.f;
            short8 bA[5], bB[5];
            #pragma unroll
            for (int nb = 0; nb < 5; ++nb)
                bA[nb] = Bp[(0 * NB2 + g * 5 + nb) * 64 + lane];
            #pragma unroll
            for (int nb = 0; nb < 5; ++nb)
                bB[nb] = Bp[(1 * NB2 + g * 5 + nb) * 64 + lane];
            #pragma unroll 1
            for (int ks = 0; ks < KS2; ks += 2) {
                short8 af = *(const short8*)&Elds[arow * ESTR + ks * 32 + ach];
                #pragma unroll
                for (int nb = 0; nb < 5; ++nb)
                    acc[nb] = __builtin_amdgcn_mfma_f32_16x16x32_bf16(af, bA[nb], acc[nb], 0, 0, 0);
                if (ks + 2 < KS2)
                    #pragma unroll
                    for (int nb = 0; nb < 5; ++nb)
                        bA[nb] = Bp[((ks + 2) * NB2 + g * 5 + nb) * 64 + lane];
                short8 af2 = *(const short8*)&Elds[arow * ESTR + (ks + 1) * 32 + ach];
                #pragma unroll
                for (int nb = 0; nb < 5; ++nb)
                    acc[nb] = __builtin_amdgcn_mfma_f32_16x16x32_bf16(af2, bB[nb], acc[nb], 0, 0, 0);
                if (ks + 3 < KS2)
                    #pragma unroll
                    for (int nb = 0; nb < 5; ++nb)
                        bB[nb] = Bp[((ks + 3) * NB2 + g * 5 + nb) * 64 + lane];
            }
            // transpose via private scratch (program-order ds deps, no barrier)
            #pragma unroll
            for (int nb = 0; nb < 5; ++nb)
                #pragma unroll
                for (int rg = 0; rg < 4; ++rg)
                    Sc[(drow + rg) * 80 + nb * 16 + dcol] = f2bf(acc[nb][rg]);
            #pragma unroll
            for (int j = 0; j < 3; ++j) {
                int idx = lane + j * 64;     // 160 uint4 chunks (16 rows x 10)
                if (idx < 160) {
                    int row = idx / 10, ch = idx - row * 10;
                    ((uint4*)P)[(size_t)(t0 + row) * 40 + g * 10 + ch] =
                        *(const uint4*)&Sc[row * 80 + ch * 8];
                }
            }
        }
    } else if (bid < NB_PROJ + NB_POSP) {
        // ---- pos-proj: P1/P2[d][k*64+o] = sum_c pos[d][c]*conv_w[o][300+tb*16+c][k] ----
        int base = (bid - NB_PROJ) * 512;
        #pragma unroll 1
        for (int j = 0; j < 8; ++j) {
            int idx = base + lane + j * 64;          // < 327680
            int tb = idx / (POS_MAX * PSTR);
            int r = idx % (POS_MAX * PSTR);
            int d = r / PSTR, col = r % PSTR;
            int k = col >> 6, o = col & 63;
            float v = 0.f;
            if (o < CNN_OUT) {
                const float* pr = pos + d * POS_D;
                const float* wb = conv_w + o * (C_IN * KW) + (EMB_D + tb * POS_D) * KW + k;
                #pragma unroll
                for (int c = 0; c < POS_D; ++c) v += pr[c] * wb[c * KW];
            }
            (tb ? P2 : P1)[d * PSTR + col] = f2bf(v);
        }
    } else {
        // ---- distances: one sentence per block, 8 positions per lane ----
        int* lst1 = (int*)smem;                  // 2048
        int* lst2 = (int*)(smem + 2048);         // 2048
        int* cnts = (int*)(smem + 4096);         // 2 ints
        int b = bid - NB_PROJ - NB_POSP;
        if (lane < 2) cnts[lane] = 0;
        __syncthreads();
        int e1 = *e1p, e2 = *e2p;
        int toks[8];
        #pragma unroll
        for (int j = 0; j < 8; ++j) {
            int s = lane + j * 64;
            toks[j] = tokens[b * SS + s];
            if (toks[j] == e1) lst1[atomicAdd(&cnts[0], 1)] = s;
            if (toks[j] == e2) lst2[atomicAdd(&cnts[1], 1)] = s;
        }
        __syncthreads();
        int n1 = cnts[0], n2 = cnts[1];
        #pragma unroll 1
        for (int j = 0; j < 8; ++j) {
            int s = lane + j * 64;
            int dd1 = POS_MAX - 1;
            for (int i = 0; i < n1; ++i) dd1 = min(dd1, abs(s - lst1[i]));
            int dd2 = POS_MAX - 1;
            for (int i = 0; i < n2; ++i) dd2 = min(dd2, abs(s - lst2[i]));
            d1[b * SS + s] = dd1;
            d2[b * SS + s] = dd2;
        }
    }
}

// ---------------- K2: conv-as-gather-add + relu + maxpool (NO MFMA) ----------------
// Block: 512 thr; tile = 64 output positions of one sentence. Stage 68 combined rows
// F[sp] = sa*(P[tok]) + sp*(P1[d1]+P2[d2]) in bf16 LDS, then per output: 5 b128 LDS
// reads + 80 adds; wave-shfl max over s; cross-wave max in LDS; 1 atomicMax per o.
__global__ __launch_bounds__(512, 4) void k_conv(const int* __restrict__ tokens,
                                                 const int* __restrict__ d1,
                                                 const int* __restrict__ d2,
                                                 const int* __restrict__ rowz,
                                                 const unsigned short* __restrict__ P,
                                                 const unsigned short* __restrict__ P1,
                                                 const unsigned short* __restrict__ P2,
                                                 const float* __restrict__ conv_b,
                                                 float* __restrict__ ymax) {
    __shared__ __align__(16) unsigned short F[FROWS * FSTR2];   // 44,608 B
    __shared__ int td[FROWS], i1d[FROWS], i2d[FROWS];
    __shared__ float sad[FROWS], spd[FROWS];
    __shared__ float Rm[8][64];
    int tid = threadIdx.x, lane = tid & 63, w = tid >> 6;
    int b = blockIdx.x >> 3, sb = blockIdx.x & 7;
    int s0 = sb * MROWS;

    // ---- phase 0: row descriptors ----
    if (tid < FROWS) {
        int sp = s0 - 2 + tid;
        bool valid = (sp >= 0 && sp < SS);
        int t = valid ? tokens[b * SS + sp] : 0;
        td[tid] = t;
        i1d[tid] = valid ? d1[b * SS + sp] : 0;
        i2d[tid] = valid ? d2[b * SS + sp] : 0;
        sad[tid] = valid ? 1.f : 0.f;
        spd[tid] = (valid && !rowz[t]) ? 1.f : 0.f;
    }
    __syncthreads();

    // ---- phase 1: gather 3 tables + combine -> F (68 rows x 40 uint4) ----
    const uint4* Pp  = (const uint4*)P;
    const uint4* P1p = (const uint4*)P1;
    const uint4* P2p = (const uint4*)P2;
    #pragma unroll
    for (int j = 0; j < 6; ++j) {
        int idx = tid + j * 512;
        if (idx < FROWS * 40) {
            int row = idx / 40, ch = idx % 40;
            uint4 a  = Pp[(size_t)td[row] * 40 + ch];
            uint4 bv = P1p[i1d[row] * 40 + ch];
            uint4 cv = P2p[i2d[row] * 40 + ch];
            float sa = sad[row], sp = spd[row];
            uint4 o;
            o.x = comb(a.x, bv.x, cv.x, sa, sp);
            o.y = comb(a.y, bv.y, cv.y, sa, sp);
            o.z = comb(a.z, bv.z, cv.z, sa, sp);
            o.w = comb(a.w, bv.w, cv.w, sa, sp);
            *(uint4*)&F[row * FSTR2 + ch * 8] = o;
        }
    }
    __syncthreads();

    // ---- phase 2: conv sum + max over s ----
    // thread: s = tid>>3 (0..63), og = (tid>>1)&3, h = tid&1 -> o = og*16 + h*8 + i
    int s = tid >> 3, og = (tid >> 1) & 3, h = tid & 1;
    float acc[8];
    #pragma unroll
    for (int i = 0; i < 8; ++i) acc[i] = 0.f;
    #pragma unroll
    for (int k = 0; k < KW; ++k) {
        uint4 v = *(const uint4*)&F[(s + k) * FSTR2 + k * 64 + og * 16 + h * 8];
        acc[0] += bflo(v.x); acc[1] += bfhi(v.x);
        acc[2] += bflo(v.y); acc[3] += bfhi(v.y);
        acc[4] += bflo(v.z); acc[5] += bfhi(v.z);
        acc[6] += bflo(v.w); acc[7] += bfhi(v.w);
    }
    #pragma unroll
    for (int i = 0; i < 8; ++i) {
        acc[i] = fmaxf(acc[i], __shfl_xor(acc[i], 8));
        acc[i] = fmaxf(acc[i], __shfl_xor(acc[i], 16));
        acc[i] = fmaxf(acc[i], __shfl_xor(acc[i], 32));
    }
    if ((lane & 56) == 0) {           // s_low == 0: 8 lanes/wave hold the per-wave max
        #pragma unroll
        for (int i = 0; i < 8; ++i)
            Rm[w][og * 16 + h * 8 + i] = acc[i];
    }
    __syncthreads();

    // ---- phase 3: cross-wave max + bias + relu + atomicMax ----
    if (tid < CNN_OUT) {
        float mx = Rm[0][tid];
        #pragma unroll
        for (int w2 = 1; w2 < 8; ++w2) mx = fmaxf(mx, Rm[w2][tid]);
        mx = fmaxf(mx + conv_b[tid], 0.f);
        atomicMax((int*)ymax + b * CNN_OUT + tid, __float_as_int(mx));
    }
}

// ---------------- K4: FC ----------------
__global__ __launch_bounds__(64) void k_fc(const float* __restrict__ ymax,
                                           const float* __restrict__ fc_w,
                                           const float* __restrict__ fc_b,
                                           float* __restrict__ out) {
    int b = blockIdx.x, n = threadIdx.x;
    if (n < NCLASS) {
        float a = fc_b[n];
        #pragma unroll
        for (int o = 0; o < CNN_OUT; ++o)
            a += ymax[b * CNN_OUT + o] * fc_w[n * CNN_OUT + o];
        out[b * NCLASS + n] = a;
    }
}

extern "C" void kernel_launch(void* const* d_in, const int* in_sizes, int n_in,
                              void* d_out, int out_size, void* d_ws, size_t ws_size,
                              hipStream_t stream) {
    const int*   tokens  = (const int*)  d_in[0];
    const float* embed   = (const float*)d_in[1];
    const float* pos     = (const float*)d_in[2];
    const float* conv_w  = (const float*)d_in[3];
    const float* conv_b  = (const float*)d_in[4];
    const float* fc_w    = (const float*)d_in[5];
    const float* fc_b    = (const float*)d_in[6];
    const int*   e1p     = (const int*)  d_in[7];
    const int*   e2p     = (const int*)  d_in[8];
    float* out = (float*)d_out;

    char* ws = (char*)d_ws;
    size_t off = 0;
    unsigned short* P   = (unsigned short*)(ws + off); off += (size_t)VOCAB * PSTR * 2;   // 32,000,000
    unsigned short* Wf2 = (unsigned short*)(ws + off); off += (size_t)NWF2 * 2;           // 204,800
    unsigned short* P1  = (unsigned short*)(ws + off); off += (size_t)POS_MAX * PSTR * 2; // 327,680
    unsigned short* P2  = (unsigned short*)(ws + off); off += (size_t)POS_MAX * PSTR * 2;
    int*   d1     = (int*)  (ws + off); off += (size_t)BB * SS * 4;
    int*   d2     = (int*)  (ws + off); off += (size_t)BB * SS * 4;
    int*   rowzp  = (int*)  (ws + off); off += (size_t)VOCAB * 4;
    float* ymax   = (float*)(ws + off); off += (size_t)BB * CNN_OUT * 4;
    (void)ws_size; (void)in_sizes; (void)n_in; (void)out_size;

    // K0: Wf2 pack + ymax zero (every launch: atomicMax state must reset)
    hipLaunchKernelGGL(k_wf, dim3((NWF2 + BB * CNN_OUT + 255) / 256), dim3(256), 0, stream,
                       conv_w, Wf2, ymax);
    // K1: merged barrier-free proj | pos-proj | distances
    hipLaunchKernelGGL(k_merge, dim3(NB_PROJ + NB_POSP + NB_DIST), dim3(64), 0, stream,
                       embed, Wf2, P, rowzp, conv_w, pos, P1, P2, tokens, e1p, e2p, d1, d2);
    // K2: gather-add conv + relu + maxpool (no MFMA)
    hipLaunchKernelGGL(k_conv, dim3(BB * (SS / MROWS)), dim3(512), 0, stream,
                       tokens, d1, d2, rowzp, P, P1, P2, conv_b, ymax);
    // K4: FC
    hipLaunchKernelGGL(k_fc, dim3(BB), dim3(64), 0, stream, ymax, fc_w, fc_b, out);
}

// Round 15
// 63.817 us; speedup vs baseline: 1.2044x; 1.2044x over previous
//
#include <hip/hip_runtime.h>
#include <hip/hip_bf16.h>

typedef __attribute__((ext_vector_type(8))) short short8;
typedef __attribute__((ext_vector_type(4))) float floatx4;

#define BB 256
#define SS 512
#define VOCAB 50000
#define EMB_D 300
#define POS_MAX 512
#define POS_D 16
#define CNN_OUT 50
#define KW 5
#define NCLASS 10
#define C_IN 332            // EMB_D + 2*POS_D
#define KS2 10              // proj GEMM K-steps: 10 x 32 = 320 (K=300 zero-masked)
#define NB2 20              // 20 n-frags of 16 = 320 cols, layout col = k*64+o
#define NWF2 (KS2 * NB2 * 64 * 8)   // 102400 packed B elems
#define PSTR 320            // P/P1/P2 row stride in bf16 (640 B = 40 uint4)
#define EDW 324             // k_proj LDS row stride in dwords (1296 B: 4-bank row walk)
#define SSTR 328            // k_proj transpose-scratch stride (ushorts)
#define FSTR2 328           // conv LDS row stride
#define MTOK 32             // tokens per proj block
#define NCHK (MTOK * 81)    // 2592 16-B chunks staged per proj block
#define MROWS 64            // output positions per conv block
#define FROWS 68            // 64 + 2+2 halo
#define NB_PACK 225         // (102400 + 12800) / 512
#define NB_POSP 640         // 2*512*320 / 512
#define NB_DIST BB

__device__ __forceinline__ unsigned pack2bf(float x, float y) {
    __hip_bfloat162 h = __float22bfloat162_rn(make_float2(x, y));   // v_cvt_pk_bf16_f32
    return *reinterpret_cast<unsigned*>(&h);
}

__device__ __forceinline__ unsigned short f2bf(float x) {
    unsigned u = __float_as_uint(x);
    u += 0x7FFF + ((u >> 16) & 1);      // RNE
    return (unsigned short)(u >> 16);
}

__device__ __forceinline__ float bflo(unsigned u) { return __uint_as_float(u << 16); }
__device__ __forceinline__ float bfhi(unsigned u) { return __uint_as_float(u & 0xFFFF0000u); }

// F = sa*a + sp*(b+c), elementwise on packed bf16 pairs, RNE repack
__device__ __forceinline__ unsigned comb(unsigned a, unsigned b, unsigned c,
                                         float sa, float sp) {
    float rlo = sa * bflo(a) + sp * (bflo(b) + bflo(c));
    float rhi = sa * bfhi(a) + sp * (bfhi(b) + bfhi(c));
    return pack2bf(rlo, rhi);
}

__device__ __forceinline__ void gload_lds16(const float* g, void* l) {
    __builtin_amdgcn_global_load_lds(
        (const __attribute__((address_space(1))) void*)g,
        (__attribute__((address_space(3))) void*)l,
        16, 0, 0);
}

__device__ __forceinline__ short8 mk8(float4 a, float4 b) {
    union { short8 s; unsigned u[4]; } t;
    t.u[0] = pack2bf(a.x, a.y);
    t.u[1] = pack2bf(a.z, a.w);
    t.u[2] = pack2bf(b.x, b.y);
    t.u[3] = pack2bf(b.z, b.w);
    return t.s;
}

// ---------------- K0: merged prep: Wf2 pack + ymax zero | pos-proj P1/P2 | distances ----
__global__ __launch_bounds__(512) void k_prep(const float* __restrict__ conv_w,
                                              const float* __restrict__ pos,
                                              unsigned short* __restrict__ Wf2,
                                              unsigned short* __restrict__ P1,
                                              unsigned short* __restrict__ P2,
                                              float* __restrict__ ymax,
                                              const int* __restrict__ tokens,
                                              const int* __restrict__ e1p,
                                              const int* __restrict__ e2p,
                                              int* __restrict__ d1,
                                              int* __restrict__ d2) {
    __shared__ int cnt1, cnt2;
    __shared__ int lst1[SS], lst2[SS];
    int bid = blockIdx.x, tid = threadIdx.x;
    if (bid < NB_PACK) {
        // Wf2 ((ks*20+nb)*64+l)*8+j holds W[c=ks*32+(l>>4)*8+j][col=nb*16+(l&15)], col=k*64+o
        int idx = bid * 512 + tid;
        if (idx < NWF2) {
            int j = idx & 7, l = (idx >> 3) & 63;
            int rest = idx >> 9;
            int nb = rest % 20, ks = rest / 20;
            int c = ks * 32 + ((l >> 4) << 3) + j;
            int col = nb * 16 + (l & 15);
            int k = col >> 6, o = col & 63;
            float v = 0.f;
            if (c < EMB_D && o < CNN_OUT)
                v = conv_w[o * (C_IN * KW) + c * KW + k];
            Wf2[idx] = f2bf(v);
        } else if (idx < NWF2 + BB * CNN_OUT) {
            ymax[idx - NWF2] = 0.f;   // relu >= 0: 0 is identity for the max
        }
    } else if (bid < NB_PACK + NB_POSP) {
        // P1/P2[d][k*64+o] = sum_c pos[d][c] * conv_w[o][300 + tb*16 + c][k]
        int idx = (bid - NB_PACK) * 512 + tid;          // < 327680
        int tb = idx / (POS_MAX * PSTR);
        int r = idx % (POS_MAX * PSTR);
        int d = r / PSTR, col = r % PSTR;
        int k = col >> 6, o = col & 63;
        float v = 0.f;
        if (o < CNN_OUT) {
            const float* pr = pos + d * POS_D;
            const float* wb = conv_w + o * (C_IN * KW) + (EMB_D + tb * POS_D) * KW + k;
            #pragma unroll
            for (int c = 0; c < POS_D; ++c) v += pr[c] * wb[c * KW];
        }
        (tb ? P2 : P1)[d * PSTR + col] = f2bf(v);
    } else {
        // nearest-entity distances: one sentence per block
        int b = bid - NB_PACK - NB_POSP;
        int s = tid;
        if (s == 0) { cnt1 = 0; cnt2 = 0; }
        __syncthreads();
        int tok = tokens[b * SS + s];
        int e1 = *e1p, e2 = *e2p;
        if (tok == e1) lst1[atomicAdd(&cnt1, 1)] = s;
        if (tok == e2) lst2[atomicAdd(&cnt2, 1)] = s;
        __syncthreads();
        int dd1 = POS_MAX - 1;
        int n1 = cnt1;
        for (int i = 0; i < n1; ++i) dd1 = min(dd1, abs(s - lst1[i]));
        int dd2 = POS_MAX - 1;
        int n2 = cnt2;
        for (int i = 0; i < n2; ++i) dd2 = min(dd2, abs(s - lst2[i]));
        d1[b * SS + s] = dd1;
        d2[b * SS + s] = dd2;
    }
}

// ---------------- K1: projection GEMM via global_load_lds staging ----------------
// 256 thr = 4 waves; 32 tokens x 320 cols. E rows for the tile are CONTIGUOUS in global
// memory -> DMA-stage 41 KB fp32 straight into LDS (41 wave-issues of 1 KB, no VGPR
// round-trip, no cvt chain). bf16 conversion happens at fragment build (cvt_pk x4,
// hidden under MFMA). ks=9 masks cols 300..319 in-register. rowz via LDS read-back.
__global__ __launch_bounds__(256, 2) void k_proj(const float* __restrict__ E,
                                                 const unsigned short* __restrict__ Wf2,
                                                 unsigned short* __restrict__ P,
                                                 int* __restrict__ rowz) {
    __shared__ __align__(16) char smem[41 * 1024];    // 41,984 B
    float* Ef = (float*)smem;                          // [32][324] fp32 (stride 1296 B)
    int tid = threadIdx.x, lane = tid & 63, w = tid >> 6;
    int t0 = blockIdx.x * MTOK;

    // ---- stage: async DMA, wave w issues chunks i = w, w+4, ... (41 total) ----
    for (int i = w; i < 41; i += 4) {
        int chunk = min(i * 64 + lane, NCHK - 1);
        int r = chunk / 81, c = chunk % 81;
        int rv = min(t0 + r, VOCAB - 1) - t0;          // clamp rows past vocab end
        int cc = min(c, 74);                           // clamp pad cols (zeroed via ks=9 mask)
        const float* src = E + (size_t)(t0 + rv) * EMB_D + cc * 4;
        gload_lds16(src, smem + i * 1024);
    }
    __syncthreads();                                   // vmcnt drain + barrier

    // ---- rowz: read back rows (8 threads/row), 8-lane ballot groups ----
    {
        int row = tid >> 3, q = tid & 7;
        bool nz = false;
        #pragma unroll
        for (int i = 0; i < 10; ++i) {
            int c4 = q + i * 8;
            if (c4 < 75) {
                float4 v = *(const float4*)&Ef[row * EDW + c4 * 4];
                nz |= (v.x != 0.f) | (v.y != 0.f) | (v.z != 0.f) | (v.w != 0.f);
            }
        }
        unsigned long long bal = __ballot(nz);
        int g = lane >> 3;
        int t = t0 + row;
        if (q == 0 && t < VOCAB)
            rowz[t] = (((bal >> (g * 8)) & 0xFFULL) == 0ULL) ? 1 : 0;
    }

    // ---- MFMA: wave w owns n-frags [w*5, w*5+5), 2 m-frags; 10 K-steps ----
    floatx4 acc[2][5];
    #pragma unroll
    for (int mm = 0; mm < 2; ++mm)
        #pragma unroll
        for (int nb = 0; nb < 5; ++nb) acc[mm][nb] = (floatx4)0.f;

    int arow = lane & 15, ach = (lane >> 4) * 8;
    const short8* Bp = (const short8*)Wf2;

    short8 bA[5], bB[5];
    #pragma unroll
    for (int nb = 0; nb < 5; ++nb)
        bA[nb] = Bp[(0 * NB2 + w * 5 + nb) * 64 + lane];
    #pragma unroll
    for (int nb = 0; nb < 5; ++nb)
        bB[nb] = Bp[(1 * NB2 + w * 5 + nb) * 64 + lane];

    auto dostep = [&](int ks, short8 (&bf)[5], int pfks, bool last) {
        short8 af[2];
        if (!last) {
            #pragma unroll
            for (int mm = 0; mm < 2; ++mm) {
                const float* rp = Ef + (mm * 16 + arow) * EDW + ks * 32 + ach;
                af[mm] = mk8(*(const float4*)rp, *(const float4*)(rp + 4));
            }
        } else {   // ks=9: cols 288..319, only 288..299 valid
            int hv = lane >> 4;
            float4 z = make_float4(0.f, 0.f, 0.f, 0.f);
            #pragma unroll
            for (int mm = 0; mm < 2; ++mm) {
                const float* rp = Ef + (mm * 16 + arow) * EDW + 288 + ach;
                float4 f0 = (hv <= 1) ? *(const float4*)rp : z;
                float4 f1 = (hv == 0) ? *(const float4*)(rp + 4) : z;
                af[mm] = mk8(f0, f1);
            }
        }
        #pragma unroll
        for (int mm = 0; mm < 2; ++mm)
            #pragma unroll
            for (int nb = 0; nb < 5; ++nb)
                acc[mm][nb] = __builtin_amdgcn_mfma_f32_16x16x32_bf16(af[mm], bf[nb], acc[mm][nb], 0, 0, 0);
        if (pfks < KS2) {
            #pragma unroll
            for (int nb = 0; nb < 5; ++nb)
                bf[nb] = Bp[(pfks * NB2 + w * 5 + nb) * 64 + lane];
        }
    };

    #pragma unroll 1
    for (int ks = 0; ks < 8; ks += 2) {
        dostep(ks, bA, ks + 2, false);
        dostep(ks + 1, bB, ks + 3, false);
    }
    dostep(8, bA, KS2, false);
    dostep(9, bB, KS2, true);

    // ---- transpose through LDS (reuse smem as ushort scratch), coalesced 16B stores ----
    __syncthreads();                  // all Ef reads done
    unsigned short* Sc = (unsigned short*)smem;       // [32][328] ushort (21 KB)
    int drow = (lane >> 4) * 4, dcol = lane & 15;
    #pragma unroll
    for (int mm = 0; mm < 2; ++mm)
        #pragma unroll
        for (int nb = 0; nb < 5; ++nb)
            #pragma unroll
            for (int rg = 0; rg < 4; ++rg)
                Sc[(mm * 16 + drow + rg) * SSTR + (w * 5 + nb) * 16 + dcol] = f2bf(acc[mm][nb][rg]);
    __syncthreads();
    #pragma unroll
    for (int j = 0; j < 5; ++j) {
        int idx = tid + j * 256;      // < 1280 = 32 rows x 40 uint4
        int row = idx / 40, ch = idx - row * 40;
        int tt = t0 + row;
        if (tt < VOCAB)
            ((uint4*)P)[(size_t)tt * 40 + ch] = *(const uint4*)&Sc[row * SSTR + ch * 8];
    }
}

// ---------------- K2: conv-as-gather-add + relu + maxpool (NO MFMA) ----------------
__global__ __launch_bounds__(512, 4) void k_conv(const int* __restrict__ tokens,
                                                 const int* __restrict__ d1,
                                                 const int* __restrict__ d2,
                                                 const int* __restrict__ rowz,
                                                 const unsigned short* __restrict__ P,
                                                 const unsigned short* __restrict__ P1,
                                                 const unsigned short* __restrict__ P2,
                                                 const float* __restrict__ conv_b,
                                                 float* __restrict__ ymax) {
    __shared__ __align__(16) unsigned short F[FROWS * FSTR2];   // 44,608 B
    __shared__ int td[FROWS], i1d[FROWS], i2d[FROWS];
    __shared__ float sad[FROWS], spd[FROWS];
    __shared__ float Rm[8][64];
    int tid = threadIdx.x, lane = tid & 63, w = tid >> 6;
    int b = blockIdx.x >> 3, sb = blockIdx.x & 7;
    int s0 = sb * MROWS;

    // ---- phase 0: row descriptors ----
    if (tid < FROWS) {
        int sp = s0 - 2 + tid;
        bool valid = (sp >= 0 && sp < SS);
        int t = valid ? tokens[b * SS + sp] : 0;
        td[tid] = t;
        i1d[tid] = valid ? d1[b * SS + sp] : 0;
        i2d[tid] = valid ? d2[b * SS + sp] : 0;
        sad[tid] = valid ? 1.f : 0.f;
        spd[tid] = (valid && !rowz[t]) ? 1.f : 0.f;
    }
    __syncthreads();

    // ---- phase 1: gather 3 tables + combine -> F (68 rows x 40 uint4) ----
    const uint4* Pp  = (const uint4*)P;
    const uint4* P1p = (const uint4*)P1;
    const uint4* P2p = (const uint4*)P2;
    #pragma unroll
    for (int j = 0; j < 6; ++j) {
        int idx = tid + j * 512;
        if (idx < FROWS * 40) {
            int row = idx / 40, ch = idx % 40;
            uint4 a  = Pp[(size_t)td[row] * 40 + ch];
            uint4 bv = P1p[i1d[row] * 40 + ch];
            uint4 cv = P2p[i2d[row] * 40 + ch];
            float sa = sad[row], sp = spd[row];
            uint4 o;
            o.x = comb(a.x, bv.x, cv.x, sa, sp);
            o.y = comb(a.y, bv.y, cv.y, sa, sp);
            o.z = comb(a.z, bv.z, cv.z, sa, sp);
            o.w = comb(a.w, bv.w, cv.w, sa, sp);
            *(uint4*)&F[row * FSTR2 + ch * 8] = o;
        }
    }
    __syncthreads();

    // ---- phase 2: conv sum + max over s ----
    int s = tid >> 3, og = (tid >> 1) & 3, h = tid & 1;
    float acc[8];
    #pragma unroll
    for (int i = 0; i < 8; ++i) acc[i] = 0.f;
    #pragma unroll
    for (int k = 0; k < KW; ++k) {
        uint4 v = *(const uint4*)&F[(s + k) * FSTR2 + k * 64 + og * 16 + h * 8];
        acc[0] += bflo(v.x); acc[1] += bfhi(v.x);
        acc[2] += bflo(v.y); acc[3] += bfhi(v.y);
        acc[4] += bflo(v.z); acc[5] += bfhi(v.z);
        acc[6] += bflo(v.w); acc[7] += bfhi(v.w);
    }
    #pragma unroll
    for (int i = 0; i < 8; ++i) {
        acc[i] = fmaxf(acc[i], __shfl_xor(acc[i], 8));
        acc[i] = fmaxf(acc[i], __shfl_xor(acc[i], 16));
        acc[i] = fmaxf(acc[i], __shfl_xor(acc[i], 32));
    }
    if ((lane & 56) == 0) {
        #pragma unroll
        for (int i = 0; i < 8; ++i)
            Rm[w][og * 16 + h * 8 + i] = acc[i];
    }
    __syncthreads();

    // ---- phase 3: cross-wave max + bias + relu + atomicMax ----
    if (tid < CNN_OUT) {
        float mx = Rm[0][tid];
        #pragma unroll
        for (int w2 = 1; w2 < 8; ++w2) mx = fmaxf(mx, Rm[w2][tid]);
        mx = fmaxf(mx + conv_b[tid], 0.f);
        atomicMax((int*)ymax + b * CNN_OUT + tid, __float_as_int(mx));
    }
}

// ---------------- K4: FC ----------------
__global__ __launch_bounds__(64) void k_fc(const float* __restrict__ ymax,
                                           const float* __restrict__ fc_w,
                                           const float* __restrict__ fc_b,
                                           float* __restrict__ out) {
    int b = blockIdx.x, n = threadIdx.x;
    if (n < NCLASS) {
        float a = fc_b[n];
        #pragma unroll
        for (int o = 0; o < CNN_OUT; ++o)
            a += ymax[b * CNN_OUT + o] * fc_w[n * CNN_OUT + o];
        out[b * NCLASS + n] = a;
    }
}

extern "C" void kernel_launch(void* const* d_in, const int* in_sizes, int n_in,
                              void* d_out, int out_size, void* d_ws, size_t ws_size,
                              hipStream_t stream) {
    const int*   tokens  = (const int*)  d_in[0];
    const float* embed   = (const float*)d_in[1];
    const float* pos     = (const float*)d_in[2];
    const float* conv_w  = (const float*)d_in[3];
    const float* conv_b  = (const float*)d_in[4];
    const float* fc_w    = (const float*)d_in[5];
    const float* fc_b    = (const float*)d_in[6];
    const int*   e1p     = (const int*)  d_in[7];
    const int*   e2p     = (const int*)  d_in[8];
    float* out = (float*)d_out;

    char* ws = (char*)d_ws;
    size_t off = 0;
    unsigned short* P   = (unsigned short*)(ws + off); off += (size_t)VOCAB * PSTR * 2;   // 32,000,000
    unsigned short* Wf2 = (unsigned short*)(ws + off); off += (size_t)NWF2 * 2;           // 204,800
    unsigned short* P1  = (unsigned short*)(ws + off); off += (size_t)POS_MAX * PSTR * 2; // 327,680
    unsigned short* P2  = (unsigned short*)(ws + off); off += (size_t)POS_MAX * PSTR * 2;
    int*   d1     = (int*)  (ws + off); off += (size_t)BB * SS * 4;
    int*   d2     = (int*)  (ws + off); off += (size_t)BB * SS * 4;
    int*   rowzp  = (int*)  (ws + off); off += (size_t)VOCAB * 4;
    float* ymax   = (float*)(ws + off); off += (size_t)BB * CNN_OUT * 4;
    (void)ws_size; (void)in_sizes; (void)n_in; (void)out_size;

    // K0: merged prep (Wf2 pack + ymax reset | P1/P2 pos-proj | distances)
    hipLaunchKernelGGL(k_prep, dim3(NB_PACK + NB_POSP + NB_DIST), dim3(512), 0, stream,
                       conv_w, pos, Wf2, P1, P2, ymax, tokens, e1p, e2p, d1, d2);
    // K1: projection GEMM over vocab (DMA-staged)
    hipLaunchKernelGGL(k_proj, dim3((VOCAB + MTOK - 1) / MTOK), dim3(256), 0, stream,
                       embed, Wf2, P, rowzp);
    // K2: gather-add conv + relu + maxpool (no MFMA)
    hipLaunchKernelGGL(k_conv, dim3(BB * (SS / MROWS)), dim3(512), 0, stream,
                       tokens, d1, d2, rowzp, P, P1, P2, conv_b, ymax);
    // K4: FC
    hipLaunchKernelGGL(k_fc, dim3(BB), dim3(64), 0, stream, ymax, fc_w, fc_b, out);
}

// Round 16
// 63.293 us; speedup vs baseline: 1.2144x; 1.0083x over previous
//
#include <hip/hip_runtime.h>
#include <hip/hip_bf16.h>

typedef __attribute__((ext_vector_type(8))) short short8;
typedef __attribute__((ext_vector_type(4))) float floatx4;

#define BB 256
#define SS 512
#define VOCAB 50000
#define EMB_D 300
#define POS_MAX 512
#define POS_D 16
#define CNN_OUT 50
#define KW 5
#define NCLASS 10
#define C_IN 332            // EMB_D + 2*POS_D
#define KS2 10              // proj GEMM K-steps: 10 x 32 = 320 (K=300 zero-padded)
#define NB2 20              // 20 n-frags of 16 = 320 cols, layout col = k*64+o
#define NWF2 (KS2 * NB2 * 64 * 8)   // 102400 packed B elems
#define PSTR 320            // P/P1/P2 row stride in bf16 (640 B = 40 uint4)
#define ESTR 328            // proj LDS row stride (ushorts; 656B -> 4-bank row walk)
#define FSTR2 328           // conv LDS row stride (same reasoning)
#define MTOK 32             // tokens per proj block
#define MROWS 64            // output positions per conv block
#define FROWS 68            // 64 + 2+2 halo
#define NB_PACK 225         // (102400 + 12800) / 512
#define NB_POSP 640         // 2*512*320 / 512
#define NB_DIST BB

__device__ __forceinline__ unsigned pack2bf(float x, float y) {
    __hip_bfloat162 h = __float22bfloat162_rn(make_float2(x, y));   // v_cvt_pk_bf16_f32
    return *reinterpret_cast<unsigned*>(&h);
}

__device__ __forceinline__ unsigned short f2bf(float x) {
    unsigned u = __float_as_uint(x);
    u += 0x7FFF + ((u >> 16) & 1);      // RNE
    return (unsigned short)(u >> 16);
}

__device__ __forceinline__ float bflo(unsigned u) { return __uint_as_float(u << 16); }
__device__ __forceinline__ float bfhi(unsigned u) { return __uint_as_float(u & 0xFFFF0000u); }

// F = sa*a + sp*(b+c), elementwise on packed bf16 pairs, RNE repack
__device__ __forceinline__ unsigned comb(unsigned a, unsigned b, unsigned c,
                                         float sa, float sp) {
    float rlo = sa * bflo(a) + sp * (bflo(b) + bflo(c));
    float rhi = sa * bfhi(a) + sp * (bfhi(b) + bfhi(c));
    return pack2bf(rlo, rhi);
}

// ---------------- K0: merged prep: Wf2 pack + ymax zero | pos-proj P1/P2 | distances ----
__global__ __launch_bounds__(512) void k_prep(const float* __restrict__ conv_w,
                                              const float* __restrict__ pos,
                                              unsigned short* __restrict__ Wf2,
                                              unsigned short* __restrict__ P1,
                                              unsigned short* __restrict__ P2,
                                              float* __restrict__ ymax,
                                              const int* __restrict__ tokens,
                                              const int* __restrict__ e1p,
                                              const int* __restrict__ e2p,
                                              int* __restrict__ d1,
                                              int* __restrict__ d2) {
    __shared__ int cnt1, cnt2;
    __shared__ int lst1[SS], lst2[SS];
    int bid = blockIdx.x, tid = threadIdx.x;
    if (bid < NB_PACK) {
        // Wf2 ((ks*20+nb)*64+l)*8+j holds W[c=ks*32+(l>>4)*8+j][col=nb*16+(l&15)], col=k*64+o
        int idx = bid * 512 + tid;
        if (idx < NWF2) {
            int j = idx & 7, l = (idx >> 3) & 63;
            int rest = idx >> 9;
            int nb = rest % 20, ks = rest / 20;
            int c = ks * 32 + ((l >> 4) << 3) + j;
            int col = nb * 16 + (l & 15);
            int k = col >> 6, o = col & 63;
            float v = 0.f;
            if (c < EMB_D && o < CNN_OUT)
                v = conv_w[o * (C_IN * KW) + c * KW + k];
            Wf2[idx] = f2bf(v);
        } else if (idx < NWF2 + BB * CNN_OUT) {
            ymax[idx - NWF2] = 0.f;   // relu >= 0: 0 is identity for the max
        }
    } else if (bid < NB_PACK + NB_POSP) {
        // P1/P2[d][k*64+o] = sum_c pos[d][c] * conv_w[o][300 + tb*16 + c][k]
        int idx = (bid - NB_PACK) * 512 + tid;          // < 327680
        int tb = idx / (POS_MAX * PSTR);
        int r = idx % (POS_MAX * PSTR);
        int d = r / PSTR, col = r % PSTR;
        int k = col >> 6, o = col & 63;
        float v = 0.f;
        if (o < CNN_OUT) {
            const float* pr = pos + d * POS_D;
            const float* wb = conv_w + o * (C_IN * KW) + (EMB_D + tb * POS_D) * KW + k;
            #pragma unroll
            for (int c = 0; c < POS_D; ++c) v += pr[c] * wb[c * KW];
        }
        (tb ? P2 : P1)[d * PSTR + col] = f2bf(v);
    } else {
        // nearest-entity distances: one sentence per block
        int b = bid - NB_PACK - NB_POSP;
        int s = tid;
        if (s == 0) { cnt1 = 0; cnt2 = 0; }
        __syncthreads();
        int tok = tokens[b * SS + s];
        int e1 = *e1p, e2 = *e2p;
        if (tok == e1) lst1[atomicAdd(&cnt1, 1)] = s;
        if (tok == e2) lst2[atomicAdd(&cnt2, 1)] = s;
        __syncthreads();
        int dd1 = POS_MAX - 1;
        int n1 = cnt1;
        for (int i = 0; i < n1; ++i) dd1 = min(dd1, abs(s - lst1[i]));
        int dd2 = POS_MAX - 1;
        int n2 = cnt2;
        for (int i = 0; i < n2; ++i) dd2 = min(dd2, abs(s - lst2[i]));
        d1[b * SS + s] = dd1;
        d2[b * SS + s] = dd2;
    }
}

// ---------------- K1: projection GEMM P[t][k*64+o] = sum_c E[t,c]*W[o,c,k] + rowz -------
// 256 thr = 4 waves; tile 32 tokens x 320 cols (LDS 21 KB).
// Staging: flat coalesced (R13). K-loop FULLY UNROLLED, no manual ping-pong: with the
// whole dataflow visible and a 256-VGPR budget, the compiler hoists B-loads to maximum
// depth (R13's unroll-1 ping-pong capped depth at 2 -> ~150cyc exposed L2 latency/step).
__global__ __launch_bounds__(256, 2) void k_proj(const float* __restrict__ E,
                                                 const unsigned short* __restrict__ Wf2,
                                                 unsigned short* __restrict__ P,
                                                 int* __restrict__ rowz) {
    __shared__ __align__(16) unsigned short Elds[MTOK * ESTR];   // 20,992 B
    __shared__ int nzf[MTOK];
    int tid = threadIdx.x, lane = tid & 63, w = tid >> 6;
    int t0 = blockIdx.x * MTOK;

    if (tid < MTOK) nzf[tid] = 0;
    __syncthreads();

    // ---- stage: flat coalesced loads (2400 float4 chunks over 256 threads) ----
    float4 v[10];
    int vrow[10], vc4[10];
    bool vok[10];
    #pragma unroll
    for (int j = 0; j < 10; ++j) {
        int idx = tid + j * 256;
        vok[j] = (idx < MTOK * 75);
        int row = idx / 75, c4 = idx - row * 75;
        vrow[j] = row; vc4[j] = c4;
        int t = t0 + row;
        v[j] = (vok[j] && t < VOCAB)
             ? ((const float4*)(E + (size_t)t * EMB_D))[c4]
             : make_float4(0.f, 0.f, 0.f, 0.f);
    }
    #pragma unroll
    for (int j = 0; j < 10; ++j) {
        if (vok[j]) {
            bool nz = (v[j].x != 0.f) | (v[j].y != 0.f) | (v[j].z != 0.f) | (v[j].w != 0.f);
            if (nz) nzf[vrow[j]] = 1;               // benign race: any-write-sets
            *(uint2*)&Elds[vrow[j] * ESTR + vc4[j] * 4] =
                make_uint2(pack2bf(v[j].x, v[j].y), pack2bf(v[j].z, v[j].w));
        }
    }
    if (tid < MTOK * 5) {   // zero-pad K cols 300..319 (5 uint2 per row)
        int row = tid / 5, u = tid - row * 5;
        *(uint2*)&Elds[row * ESTR + 300 + u * 4] = make_uint2(0u, 0u);
    }
    __syncthreads();

    // rowz from flags
    if (tid < MTOK) {
        int t = t0 + tid;
        if (t < VOCAB) rowz[t] = nzf[tid] ? 0 : 1;
    }

    // ---- MFMA: wave w owns n-frags [w*5, w*5+5), 2 m-frags; 10 K-steps, FULL unroll ----
    floatx4 acc[2][5];
    #pragma unroll
    for (int mm = 0; mm < 2; ++mm)
        #pragma unroll
        for (int nb = 0; nb < 5; ++nb) acc[mm][nb] = (floatx4)0.f;

    int arow = lane & 15, ach = (lane >> 4) * 8;
    const short8* Bp = (const short8*)Wf2;

    #pragma unroll
    for (int ks = 0; ks < KS2; ++ks) {
        short8 af[2];
        #pragma unroll
        for (int mm = 0; mm < 2; ++mm)
            af[mm] = *(const short8*)&Elds[(mm * 16 + arow) * ESTR + ks * 32 + ach];
        #pragma unroll
        for (int nb = 0; nb < 5; ++nb) {
            short8 bf = Bp[(ks * NB2 + w * 5 + nb) * 64 + lane];
            #pragma unroll
            for (int mm = 0; mm < 2; ++mm)
                acc[mm][nb] = __builtin_amdgcn_mfma_f32_16x16x32_bf16(af[mm], bf, acc[mm][nb], 0, 0, 0);
        }
    }

    // ---- transpose through LDS (reuse Elds), then coalesced 16B stores ----
    __syncthreads();                  // all A-reads done
    int drow = (lane >> 4) * 4, dcol = lane & 15;
    #pragma unroll
    for (int mm = 0; mm < 2; ++mm)
        #pragma unroll
        for (int nb = 0; nb < 5; ++nb)
            #pragma unroll
            for (int rg = 0; rg < 4; ++rg)
                Elds[(mm * 16 + drow + rg) * ESTR + (w * 5 + nb) * 16 + dcol] = f2bf(acc[mm][nb][rg]);
    __syncthreads();
    #pragma unroll
    for (int j = 0; j < 5; ++j) {
        int idx = tid + j * 256;      // < 1280 = 32 rows x 40 uint4
        int row = idx / 40, ch = idx - row * 40;
        int tt = t0 + row;
        if (tt < VOCAB)
            ((uint4*)P)[(size_t)tt * 40 + ch] = *(const uint4*)&Elds[row * ESTR + ch * 8];
    }
}

// ---------------- K2: conv-as-gather-add + relu + maxpool (NO MFMA) ----------------
// Block: 512 thr; tile = 64 output positions of one sentence. Stage 68 combined rows
// F[sp] = sa*(P[tok]) + sp*(P1[d1]+P2[d2]) in bf16 LDS, then per output: 5 b128 LDS
// reads + 80 adds; wave-shfl max over s; cross-wave max in LDS; 1 atomicMax per o.
__global__ __launch_bounds__(512, 4) void k_conv(const int* __restrict__ tokens,
                                                 const int* __restrict__ d1,
                                                 const int* __restrict__ d2,
                                                 const int* __restrict__ rowz,
                                                 const unsigned short* __restrict__ P,
                                                 const unsigned short* __restrict__ P1,
                                                 const unsigned short* __restrict__ P2,
                                                 const float* __restrict__ conv_b,
                                                 float* __restrict__ ymax) {
    __shared__ __align__(16) unsigned short F[FROWS * FSTR2];   // 44,608 B
    __shared__ int td[FROWS], i1d[FROWS], i2d[FROWS];
    __shared__ float sad[FROWS], spd[FROWS];
    __shared__ float Rm[8][64];
    int tid = threadIdx.x, lane = tid & 63, w = tid >> 6;
    int b = blockIdx.x >> 3, sb = blockIdx.x & 7;
    int s0 = sb * MROWS;

    // ---- phase 0: row descriptors ----
    if (tid < FROWS) {
        int sp = s0 - 2 + tid;
        bool valid = (sp >= 0 && sp < SS);
        int t = valid ? tokens[b * SS + sp] : 0;
        td[tid] = t;
        i1d[tid] = valid ? d1[b * SS + sp] : 0;
        i2d[tid] = valid ? d2[b * SS + sp] : 0;
        sad[tid] = valid ? 1.f : 0.f;
        spd[tid] = (valid && !rowz[t]) ? 1.f : 0.f;
    }
    __syncthreads();

    // ---- phase 1: gather 3 tables + combine -> F (68 rows x 40 uint4) ----
    const uint4* Pp  = (const uint4*)P;
    const uint4* P1p = (const uint4*)P1;
    const uint4* P2p = (const uint4*)P2;
    #pragma unroll
    for (int j = 0; j < 6; ++j) {
        int idx = tid + j * 512;
        if (idx < FROWS * 40) {
            int row = idx / 40, ch = idx % 40;
            uint4 a  = Pp[(size_t)td[row] * 40 + ch];
            uint4 bv = P1p[i1d[row] * 40 + ch];
            uint4 cv = P2p[i2d[row] * 40 + ch];
            float sa = sad[row], sp = spd[row];
            uint4 o;
            o.x = comb(a.x, bv.x, cv.x, sa, sp);
            o.y = comb(a.y, bv.y, cv.y, sa, sp);
            o.z = comb(a.z, bv.z, cv.z, sa, sp);
            o.w = comb(a.w, bv.w, cv.w, sa, sp);
            *(uint4*)&F[row * FSTR2 + ch * 8] = o;
        }
    }
    __syncthreads();

    // ---- phase 2: conv sum + max over s ----
    // thread: s = tid>>3 (0..63), og = (tid>>1)&3, h = tid&1 -> o = og*16 + h*8 + i
    int s = tid >> 3, og = (tid >> 1) & 3, h = tid & 1;
    float acc[8];
    #pragma unroll
    for (int i = 0; i < 8; ++i) acc[i] = 0.f;
    #pragma unroll
    for (int k = 0; k < KW; ++k) {
        uint4 v = *(const uint4*)&F[(s + k) * FSTR2 + k * 64 + og * 16 + h * 8];
        acc[0] += bflo(v.x); acc[1] += bfhi(v.x);
        acc[2] += bflo(v.y); acc[3] += bfhi(v.y);
        acc[4] += bflo(v.z); acc[5] += bfhi(v.z);
        acc[6] += bflo(v.w); acc[7] += bfhi(v.w);
    }
    #pragma unroll
    for (int i = 0; i < 8; ++i) {
        acc[i] = fmaxf(acc[i], __shfl_xor(acc[i], 8));
        acc[i] = fmaxf(acc[i], __shfl_xor(acc[i], 16));
        acc[i] = fmaxf(acc[i], __shfl_xor(acc[i], 32));
    }
    if ((lane & 56) == 0) {           // s_low == 0: 8 lanes/wave hold the per-wave max
        #pragma unroll
        for (int i = 0; i < 8; ++i)
            Rm[w][og * 16 + h * 8 + i] = acc[i];
    }
    __syncthreads();

    // ---- phase 3: cross-wave max + bias + relu + atomicMax ----
    if (tid < CNN_OUT) {
        float mx = Rm[0][tid];
        #pragma unroll
        for (int w2 = 1; w2 < 8; ++w2) mx = fmaxf(mx, Rm[w2][tid]);
        mx = fmaxf(mx + conv_b[tid], 0.f);
        atomicMax((int*)ymax + b * CNN_OUT + tid, __float_as_int(mx));
    }
}

// ---------------- K4: FC ----------------
__global__ __launch_bounds__(64) void k_fc(const float* __restrict__ ymax,
                                           const float* __restrict__ fc_w,
                                           const float* __restrict__ fc_b,
                                           float* __restrict__ out) {
    int b = blockIdx.x, n = threadIdx.x;
    if (n < NCLASS) {
        float a = fc_b[n];
        #pragma unroll
        for (int o = 0; o < CNN_OUT; ++o)
            a += ymax[b * CNN_OUT + o] * fc_w[n * CNN_OUT + o];
        out[b * NCLASS + n] = a;
    }
}

extern "C" void kernel_launch(void* const* d_in, const int* in_sizes, int n_in,
                              void* d_out, int out_size, void* d_ws, size_t ws_size,
                              hipStream_t stream) {
    const int*   tokens  = (const int*)  d_in[0];
    const float* embed   = (const float*)d_in[1];
    const float* pos     = (const float*)d_in[2];
    const float* conv_w  = (const float*)d_in[3];
    const float* conv_b  = (const float*)d_in[4];
    const float* fc_w    = (const float*)d_in[5];
    const float* fc_b    = (const float*)d_in[6];
    const int*   e1p     = (const int*)  d_in[7];
    const int*   e2p     = (const int*)  d_in[8];
    float* out = (float*)d_out;

    char* ws = (char*)d_ws;
    size_t off = 0;
    unsigned short* P   = (unsigned short*)(ws + off); off += (size_t)VOCAB * PSTR * 2;   // 32,000,000
    unsigned short* Wf2 = (unsigned short*)(ws + off); off += (size_t)NWF2 * 2;           // 204,800
    unsigned short* P1  = (unsigned short*)(ws + off); off += (size_t)POS_MAX * PSTR * 2; // 327,680
    unsigned short* P2  = (unsigned short*)(ws + off); off += (size_t)POS_MAX * PSTR * 2;
    int*   d1     = (int*)  (ws + off); off += (size_t)BB * SS * 4;
    int*   d2     = (int*)  (ws + off); off += (size_t)BB * SS * 4;
    int*   rowzp  = (int*)  (ws + off); off += (size_t)VOCAB * 4;
    float* ymax   = (float*)(ws + off); off += (size_t)BB * CNN_OUT * 4;
    (void)ws_size; (void)in_sizes; (void)n_in; (void)out_size;

    // K0: merged prep (Wf2 pack + ymax reset | P1/P2 pos-proj | distances)
    hipLaunchKernelGGL(k_prep, dim3(NB_PACK + NB_POSP + NB_DIST), dim3(512), 0, stream,
                       conv_w, pos, Wf2, P1, P2, ymax, tokens, e1p, e2p, d1, d2);
    // K1: projection GEMM over vocab (needs Wf2)
    hipLaunchKernelGGL(k_proj, dim3((VOCAB + MTOK - 1) / MTOK), dim3(256), 0, stream,
                       embed, Wf2, P, rowzp);
    // K2: gather-add conv + relu + maxpool (no MFMA)
    hipLaunchKernelGGL(k_conv, dim3(BB * (SS / MROWS)), dim3(512), 0, stream,
                       tokens, d1, d2, rowzp, P, P1, P2, conv_b, ymax);
    // K4: FC
    hipLaunchKernelGGL(k_fc, dim3(BB), dim3(64), 0, stream, ymax, fc_w, fc_b, out);
}

// Round 17
// 60.591 us; speedup vs baseline: 1.2685x; 1.0446x over previous
//
#include <hip/hip_runtime.h>
#include <hip/hip_bf16.h>

typedef __attribute__((ext_vector_type(8))) short short8;
typedef __attribute__((ext_vector_type(4))) float floatx4;

#define BB 256
#define SS 512
#define VOCAB 50000
#define EMB_D 300
#define POS_MAX 512
#define POS_D 16
#define CNN_OUT 50
#define KW 5
#define NCLASS 10
#define C_IN 332            // EMB_D + 2*POS_D
#define KS2 10              // proj GEMM K-steps: 10 x 32 = 320 (K=300 zero-padded)
#define NB2 20              // 20 n-frags of 16 = 320 cols, layout col = k*64+o
#define NWF2 (KS2 * NB2 * 64 * 8)   // 102400 packed B elems
#define PSTR 320            // P/P1/P2 row stride in bf16 (640 B = 40 uint4)
#define ESTR 328            // proj LDS row stride (ushorts; 656B -> 4-bank row walk)
#define FSTR2 328           // conv LDS row stride (same reasoning)
#define MTOK 32             // tokens per proj block
#define MROWS 64            // output positions per conv block
#define FROWS 68            // 64 + 2+2 halo
#define NB_PROJ 1563        // ceil(50000/32)
#define NB_POSP 1280        // 2*512*320 / 256
#define NB_DIST BB

__device__ __forceinline__ unsigned pack2bf(float x, float y) {
    __hip_bfloat162 h = __float22bfloat162_rn(make_float2(x, y));   // v_cvt_pk_bf16_f32
    return *reinterpret_cast<unsigned*>(&h);
}

__device__ __forceinline__ unsigned short f2bf(float x) {
    unsigned u = __float_as_uint(x);
    u += 0x7FFF + ((u >> 16) & 1);      // RNE
    return (unsigned short)(u >> 16);
}

__device__ __forceinline__ float bflo(unsigned u) { return __uint_as_float(u << 16); }
__device__ __forceinline__ float bfhi(unsigned u) { return __uint_as_float(u & 0xFFFF0000u); }

// F = sa*a + sp*(b+c), elementwise on packed bf16 pairs, RNE repack
__device__ __forceinline__ unsigned comb(unsigned a, unsigned b, unsigned c,
                                         float sa, float sp) {
    float rlo = sa * bflo(a) + sp * (bflo(b) + bflo(c));
    float rhi = sa * bfhi(a) + sp * (bfhi(b) + bfhi(c));
    return pack2bf(rlo, rhi);
}

// ---------------- K0: Wf2 pack + ymax zero (tiny; k_projm needs Wf2 first) ----------------
__global__ __launch_bounds__(256) void k_wf(const float* __restrict__ conv_w,
                                            unsigned short* __restrict__ Wf2,
                                            float* __restrict__ ymax) {
    int idx = blockIdx.x * 256 + threadIdx.x;
    if (idx < NWF2) {
        // ((ks*20+nb)*64+l)*8+j holds W[c=ks*32+(l>>4)*8+j][col=nb*16+(l&15)], col=k*64+o
        int j = idx & 7, l = (idx >> 3) & 63;
        int rest = idx >> 9;
        int nb = rest % 20, ks = rest / 20;
        int c = ks * 32 + ((l >> 4) << 3) + j;
        int col = nb * 16 + (l & 15);
        int k = col >> 6, o = col & 63;
        float v = 0.f;
        if (c < EMB_D && o < CNN_OUT)
            v = conv_w[o * (C_IN * KW) + c * KW + k];
        Wf2[idx] = f2bf(v);
    } else if (idx < NWF2 + BB * CNN_OUT) {
        ymax[idx - NWF2] = 0.f;   // relu >= 0: 0 is identity for the max
    }
}

// ---------------- K1: merged: proj GEMM (R13 body) | pos-proj | distances ----------------
// 256-thread blocks, role by blockIdx. pos-proj and distance blocks execute inside the
// proj waves' L3-latency bubbles (~free per the Little's-law model), removing the
// serialized k_prep dispatch.
__global__ __launch_bounds__(256, 2) void k_projm(const float* __restrict__ E,
                                                  const unsigned short* __restrict__ Wf2,
                                                  unsigned short* __restrict__ P,
                                                  int* __restrict__ rowz,
                                                  const float* __restrict__ conv_w,
                                                  const float* __restrict__ pos,
                                                  unsigned short* __restrict__ P1,
                                                  unsigned short* __restrict__ P2,
                                                  const int* __restrict__ tokens,
                                                  const int* __restrict__ e1p,
                                                  const int* __restrict__ e2p,
                                                  int* __restrict__ d1,
                                                  int* __restrict__ d2) {
    __shared__ __align__(16) char smem[21120];
    int bid = blockIdx.x, tid = threadIdx.x;

    if (bid < NB_PROJ) {
        // ================= proj: P[t][k*64+o] = sum_c E[t,c]*W[o,c,k] + rowz =================
        unsigned short* Elds = (unsigned short*)smem;        // 32*328*2 = 20,992 B
        int* nzf = (int*)(smem + 20992);                      // 32 ints
        int lane = tid & 63, w = tid >> 6;
        int t0 = bid * MTOK;

        if (tid < MTOK) nzf[tid] = 0;
        __syncthreads();

        // ---- stage: flat coalesced loads (2400 float4 chunks over 256 threads) ----
        float4 v[10];
        int vrow[10], vc4[10];
        bool vok[10];
        #pragma unroll
        for (int j = 0; j < 10; ++j) {
            int idx = tid + j * 256;
            vok[j] = (idx < MTOK * 75);
            int row = idx / 75, c4 = idx - row * 75;
            vrow[j] = row; vc4[j] = c4;
            int t = t0 + row;
            v[j] = (vok[j] && t < VOCAB)
                 ? ((const float4*)(E + (size_t)t * EMB_D))[c4]
                 : make_float4(0.f, 0.f, 0.f, 0.f);
        }
        #pragma unroll
        for (int j = 0; j < 10; ++j) {
            if (vok[j]) {
                bool nz = (v[j].x != 0.f) | (v[j].y != 0.f) | (v[j].z != 0.f) | (v[j].w != 0.f);
                if (nz) nzf[vrow[j]] = 1;               // benign race: any-write-sets
                *(uint2*)&Elds[vrow[j] * ESTR + vc4[j] * 4] =
                    make_uint2(pack2bf(v[j].x, v[j].y), pack2bf(v[j].z, v[j].w));
            }
        }
        if (tid < MTOK * 5) {   // zero-pad K cols 300..319 (5 uint2 per row)
            int row = tid / 5, u = tid - row * 5;
            *(uint2*)&Elds[row * ESTR + 300 + u * 4] = make_uint2(0u, 0u);
        }
        __syncthreads();

        // rowz from flags
        if (tid < MTOK) {
            int t = t0 + tid;
            if (t < VOCAB) rowz[t] = nzf[tid] ? 0 : 1;
        }

        // ---- MFMA: wave w owns n-frags [w*5, w*5+5), 2 m-frags; 10 K-steps ----
        floatx4 acc[2][5];
        #pragma unroll
        for (int mm = 0; mm < 2; ++mm)
            #pragma unroll
            for (int nb = 0; nb < 5; ++nb) acc[mm][nb] = (floatx4)0.f;

        int arow = lane & 15, ach = (lane >> 4) * 8;
        const short8* Bp = (const short8*)Wf2;

        short8 bA[5], bB[5];
        #pragma unroll
        for (int nb = 0; nb < 5; ++nb)
            bA[nb] = Bp[(0 * NB2 + w * 5 + nb) * 64 + lane];
        #pragma unroll
        for (int nb = 0; nb < 5; ++nb)
            bB[nb] = Bp[(1 * NB2 + w * 5 + nb) * 64 + lane];

        auto step = [&](int ks, short8 (&bf)[5], int pfks) {
            short8 af[2];
            #pragma unroll
            for (int mm = 0; mm < 2; ++mm)
                af[mm] = *(const short8*)&Elds[(mm * 16 + arow) * ESTR + ks * 32 + ach];
            #pragma unroll
            for (int mm = 0; mm < 2; ++mm)
                #pragma unroll
                for (int nb = 0; nb < 5; ++nb)
                    acc[mm][nb] = __builtin_amdgcn_mfma_f32_16x16x32_bf16(af[mm], bf[nb], acc[mm][nb], 0, 0, 0);
            if (pfks < KS2) {
                #pragma unroll
                for (int nb = 0; nb < 5; ++nb)
                    bf[nb] = Bp[(pfks * NB2 + w * 5 + nb) * 64 + lane];
            }
        };

        #pragma unroll 1
        for (int ks = 0; ks < KS2; ks += 2) {
            step(ks, bA, ks + 2);
            step(ks + 1, bB, ks + 3);
        }

        // ---- transpose through LDS (reuse Elds), then coalesced 16B stores ----
        __syncthreads();                  // all A-reads done
        int drow = (lane >> 4) * 4, dcol = lane & 15;
        #pragma unroll
        for (int mm = 0; mm < 2; ++mm)
            #pragma unroll
            for (int nb = 0; nb < 5; ++nb)
                #pragma unroll
                for (int rg = 0; rg < 4; ++rg)
                    Elds[(mm * 16 + drow + rg) * ESTR + (w * 5 + nb) * 16 + dcol] = f2bf(acc[mm][nb][rg]);
        __syncthreads();
        #pragma unroll
        for (int j = 0; j < 5; ++j) {
            int idx = tid + j * 256;      // < 1280 = 32 rows x 40 uint4
            int row = idx / 40, ch = idx - row * 40;
            int tt = t0 + row;
            if (tt < VOCAB)
                ((uint4*)P)[(size_t)tt * 40 + ch] = *(const uint4*)&Elds[row * ESTR + ch * 8];
        }
    } else if (bid < NB_PROJ + NB_POSP) {
        // ================= pos-proj: P1/P2[d][k*64+o] = sum_c pos[d][c]*W[o][300+tb*16+c][k] ===
        int idx = (bid - NB_PROJ) * 256 + tid;          // < 327680
        int tb = idx / (POS_MAX * PSTR);
        int r = idx % (POS_MAX * PSTR);
        int d = r / PSTR, col = r % PSTR;
        int k = col >> 6, o = col & 63;
        float v = 0.f;
        if (o < CNN_OUT) {
            const float* pr = pos + d * POS_D;
            const float* wb = conv_w + o * (C_IN * KW) + (EMB_D + tb * POS_D) * KW + k;
            #pragma unroll
            for (int c = 0; c < POS_D; ++c) v += pr[c] * wb[c * KW];
        }
        (tb ? P2 : P1)[d * PSTR + col] = f2bf(v);
    } else {
        // ================= distances: one sentence per block, 2 positions per thread ========
        int* lst1 = (int*)smem;                  // 2048 B
        int* lst2 = (int*)(smem + 2048);         // 2048 B
        int* cnts = (int*)(smem + 4096);         // 2 ints
        int b = bid - NB_PROJ - NB_POSP;
        if (tid < 2) cnts[tid] = 0;
        __syncthreads();
        int e1 = *e1p, e2 = *e2p;
        #pragma unroll
        for (int j = 0; j < 2; ++j) {
            int s = tid + j * 256;
            int tok = tokens[b * SS + s];
            if (tok == e1) lst1[atomicAdd(&cnts[0], 1)] = s;
            if (tok == e2) lst2[atomicAdd(&cnts[1], 1)] = s;
        }
        __syncthreads();
        int n1 = cnts[0], n2 = cnts[1];
        #pragma unroll 1
        for (int j = 0; j < 2; ++j) {
            int s = tid + j * 256;
            int dd1 = POS_MAX - 1;
            for (int i = 0; i < n1; ++i) dd1 = min(dd1, abs(s - lst1[i]));
            int dd2 = POS_MAX - 1;
            for (int i = 0; i < n2; ++i) dd2 = min(dd2, abs(s - lst2[i]));
            d1[b * SS + s] = dd1;
            d2[b * SS + s] = dd2;
        }
    }
}

// ---------------- K2: conv-as-gather-add + relu + maxpool (NO MFMA) ----------------
// Block: 512 thr; tile = 64 output positions of one sentence. Stage 68 combined rows
// F[sp] = sa*(P[tok]) + sp*(P1[d1]+P2[d2]) in bf16 LDS, then per output: 5 b128 LDS
// reads + 80 adds; wave-shfl max over s; cross-wave max in LDS; 1 atomicMax per o.
__global__ __launch_bounds__(512, 4) void k_conv(const int* __restrict__ tokens,
                                                 const int* __restrict__ d1,
                                                 const int* __restrict__ d2,
                                                 const int* __restrict__ rowz,
                                                 const unsigned short* __restrict__ P,
                                                 const unsigned short* __restrict__ P1,
                                                 const unsigned short* __restrict__ P2,
                                                 const float* __restrict__ conv_b,
                                                 float* __restrict__ ymax) {
    __shared__ __align__(16) unsigned short F[FROWS * FSTR2];   // 44,608 B
    __shared__ int td[FROWS], i1d[FROWS], i2d[FROWS];
    __shared__ float sad[FROWS], spd[FROWS];
    __shared__ float Rm[8][64];
    int tid = threadIdx.x, lane = tid & 63, w = tid >> 6;
    int b = blockIdx.x >> 3, sb = blockIdx.x & 7;
    int s0 = sb * MROWS;

    // ---- phase 0: row descriptors ----
    if (tid < FROWS) {
        int sp = s0 - 2 + tid;
        bool valid = (sp >= 0 && sp < SS);
        int t = valid ? tokens[b * SS + sp] : 0;
        td[tid] = t;
        i1d[tid] = valid ? d1[b * SS + sp] : 0;
        i2d[tid] = valid ? d2[b * SS + sp] : 0;
        sad[tid] = valid ? 1.f : 0.f;
        spd[tid] = (valid && !rowz[t]) ? 1.f : 0.f;
    }
    __syncthreads();

    // ---- phase 1: gather 3 tables + combine -> F (68 rows x 40 uint4) ----
    const uint4* Pp  = (const uint4*)P;
    const uint4* P1p = (const uint4*)P1;
    const uint4* P2p = (const uint4*)P2;
    #pragma unroll
    for (int j = 0; j < 6; ++j) {
        int idx = tid + j * 512;
        if (idx < FROWS * 40) {
            int row = idx / 40, ch = idx % 40;
            uint4 a  = Pp[(size_t)td[row] * 40 + ch];
            uint4 bv = P1p[i1d[row] * 40 + ch];
            uint4 cv = P2p[i2d[row] * 40 + ch];
            float sa = sad[row], sp = spd[row];
            uint4 o;
            o.x = comb(a.x, bv.x, cv.x, sa, sp);
            o.y = comb(a.y, bv.y, cv.y, sa, sp);
            o.z = comb(a.z, bv.z, cv.z, sa, sp);
            o.w = comb(a.w, bv.w, cv.w, sa, sp);
            *(uint4*)&F[row * FSTR2 + ch * 8] = o;
        }
    }
    __syncthreads();

    // ---- phase 2: conv sum + max over s ----
    // thread: s = tid>>3 (0..63), og = (tid>>1)&3, h = tid&1 -> o = og*16 + h*8 + i
    int s = tid >> 3, og = (tid >> 1) & 3, h = tid & 1;
    float acc[8];
    #pragma unroll
    for (int i = 0; i < 8; ++i) acc[i] = 0.f;
    #pragma unroll
    for (int k = 0; k < KW; ++k) {
        uint4 v = *(const uint4*)&F[(s + k) * FSTR2 + k * 64 + og * 16 + h * 8];
        acc[0] += bflo(v.x); acc[1] += bfhi(v.x);
        acc[2] += bflo(v.y); acc[3] += bfhi(v.y);
        acc[4] += bflo(v.z); acc[5] += bfhi(v.z);
        acc[6] += bflo(v.w); acc[7] += bfhi(v.w);
    }
    #pragma unroll
    for (int i = 0; i < 8; ++i) {
        acc[i] = fmaxf(acc[i], __shfl_xor(acc[i], 8));
        acc[i] = fmaxf(acc[i], __shfl_xor(acc[i], 16));
        acc[i] = fmaxf(acc[i], __shfl_xor(acc[i], 32));
    }
    if ((lane & 56) == 0) {           // s_low == 0: 8 lanes/wave hold the per-wave max
        #pragma unroll
        for (int i = 0; i < 8; ++i)
            Rm[w][og * 16 + h * 8 + i] = acc[i];
    }
    __syncthreads();

    // ---- phase 3: cross-wave max + bias + relu + atomicMax ----
    if (tid < CNN_OUT) {
        float mx = Rm[0][tid];
        #pragma unroll
        for (int w2 = 1; w2 < 8; ++w2) mx = fmaxf(mx, Rm[w2][tid]);
        mx = fmaxf(mx + conv_b[tid], 0.f);
        atomicMax((int*)ymax + b * CNN_OUT + tid, __float_as_int(mx));
    }
}

// ---------------- K4: FC ----------------
__global__ __launch_bounds__(64) void k_fc(const float* __restrict__ ymax,
                                           const float* __restrict__ fc_w,
                                           const float* __restrict__ fc_b,
                                           float* __restrict__ out) {
    int b = blockIdx.x, n = threadIdx.x;
    if (n < NCLASS) {
        float a = fc_b[n];
        #pragma unroll
        for (int o = 0; o < CNN_OUT; ++o)
            a += ymax[b * CNN_OUT + o] * fc_w[n * CNN_OUT + o];
        out[b * NCLASS + n] = a;
    }
}

extern "C" void kernel_launch(void* const* d_in, const int* in_sizes, int n_in,
                              void* d_out, int out_size, void* d_ws, size_t ws_size,
                              hipStream_t stream) {
    const int*   tokens  = (const int*)  d_in[0];
    const float* embed   = (const float*)d_in[1];
    const float* pos     = (const float*)d_in[2];
    const float* conv_w  = (const float*)d_in[3];
    const float* conv_b  = (const float*)d_in[4];
    const float* fc_w    = (const float*)d_in[5];
    const float* fc_b    = (const float*)d_in[6];
    const int*   e1p     = (const int*)  d_in[7];
    const int*   e2p     = (const int*)  d_in[8];
    float* out = (float*)d_out;

    char* ws = (char*)d_ws;
    size_t off = 0;
    unsigned short* P   = (unsigned short*)(ws + off); off += (size_t)VOCAB * PSTR * 2;   // 32,000,000
    unsigned short* Wf2 = (unsigned short*)(ws + off); off += (size_t)NWF2 * 2;           // 204,800
    unsigned short* P1  = (unsigned short*)(ws + off); off += (size_t)POS_MAX * PSTR * 2; // 327,680
    unsigned short* P2  = (unsigned short*)(ws + off); off += (size_t)POS_MAX * PSTR * 2;
    int*   d1     = (int*)  (ws + off); off += (size_t)BB * SS * 4;
    int*   d2     = (int*)  (ws + off); off += (size_t)BB * SS * 4;
    int*   rowzp  = (int*)  (ws + off); off += (size_t)VOCAB * 4;
    float* ymax   = (float*)(ws + off); off += (size_t)BB * CNN_OUT * 4;
    (void)ws_size; (void)in_sizes; (void)n_in; (void)out_size;

    // K0: Wf2 pack + ymax zero (every launch: atomicMax state must reset)
    hipLaunchKernelGGL(k_wf, dim3((NWF2 + BB * CNN_OUT + 255) / 256), dim3(256), 0, stream,
                       conv_w, Wf2, ymax);
    // K1: merged proj | pos-proj | distances (prep roles ride proj's latency bubbles)
    hipLaunchKernelGGL(k_projm, dim3(NB_PROJ + NB_POSP + NB_DIST), dim3(256), 0, stream,
                       embed, Wf2, P, rowzp, conv_w, pos, P1, P2, tokens, e1p, e2p, d1, d2);
    // K2: gather-add conv + relu + maxpool (no MFMA)
    hipLaunchKernelGGL(k_conv, dim3(BB * (SS / MROWS)), dim3(512), 0, stream,
                       tokens, d1, d2, rowzp, P, P1, P2, conv_b, ymax);
    // K4: FC
    hipLaunchKernelGGL(k_fc, dim3(BB), dim3(64), 0, stream, ymax, fc_w, fc_b, out);
}